// Round 11
// baseline (338.546 us; speedup 1.0000x reference)
//
#include <hip/hip_runtime.h>
#include <hip/hip_cooperative_groups.h>

namespace cg = cooperative_groups;

#define IN_DIM 128
#define OUT_DIM 64
#define NEG_SLOPE 0.01f
#define ECHUNK 4096       // edges per binning block
// bucket = node >> 8  (256 nodes per bucket)

typedef __attribute__((ext_vector_type(8))) short short8;
typedef __attribute__((ext_vector_type(4))) float floatx4;

// bf16 helpers: memory layout = 16-bit, value = bits<<16
__device__ inline float bf_lo(unsigned u) { union { unsigned i; float f; } c; c.i = u << 16; return c.f; }
__device__ inline float bf_hi(unsigned u) { union { unsigned i; float f; } c; c.i = u & 0xFFFF0000u; return c.f; }
__device__ inline unsigned short f2b(float f) {
    union { float f; unsigned i; } c; c.f = f;
    unsigned u = c.i + 0x7FFFu + ((c.i >> 16) & 1u);   // round-to-nearest-even
    return (unsigned short)(u >> 16);
}

// 2-elems-per-thread exclusive scan of column b of cntA[(chunk)][bucket] -> cntB[b][chunk], tot[b]
__device__ inline void scan_col(const int* __restrict__ cntA, int* __restrict__ cntB,
                                int* __restrict__ tot, int b, int nchunk, int nbuck,
                                int* ps, int t) {
    int j0 = 2 * t, j1 = 2 * t + 1;
    int a0 = (j0 < nchunk) ? cntA[j0 * nbuck + b] : 0;
    int a1 = (j1 < nchunk) ? cntA[j1 * nbuck + b] : 0;
    ps[t] = a0 + a1;
    __syncthreads();
    for (int d = 1; d < 256; d <<= 1) {
        int u = (t >= d) ? ps[t - d] : 0;
        __syncthreads();
        ps[t] += u;
        __syncthreads();
    }
    int excl = ps[t] - (a0 + a1);
    if (j0 < nchunk) cntB[b * nchunk + j0] = excl;
    if (j1 < nchunk) cntB[b * nchunk + j1] = excl + a0;
    if (t == 255) tot[b] = ps[255];
    __syncthreads();
}

// 2-elems-per-thread exclusive scan of tot[0..m) -> base[0..m], base[m]=total
__device__ inline void scan_base(const int* __restrict__ tot, int* __restrict__ base,
                                 int m, int* ps, int t) {
    int j0 = 2 * t, j1 = 2 * t + 1;
    int a0 = (j0 < m) ? tot[j0] : 0;
    int a1 = (j1 < m) ? tot[j1] : 0;
    ps[t] = a0 + a1;
    __syncthreads();
    for (int d = 1; d < 256; d <<= 1) {
        int u = (t >= d) ? ps[t - d] : 0;
        __syncthreads();
        ps[t] += u;
        __syncthreads();
    }
    int excl = ps[t] - (a0 + a1);
    if (j0 < m) base[j0] = excl;
    if (j1 < m) base[j1] = excl + a0;
    if (t == 255) base[m] = ps[255];
    __syncthreads();
}

// ---------------- fused CSR build: hist -> colscan -> base -> binpack -> fill ----------------
__global__ __launch_bounds__(256) void build_kernel(
    const int* __restrict__ es, const int* __restrict__ ed,
    int* cntA_d, int* cntA_s, int* cntB_d, int* cntB_s,
    int* tot_d, int* tot_s, int* base_d, int* base_s,
    int* bp_dst, unsigned char* bp_src,
    int* ds, int* off, int* csr,
    int n, int E, int nchunk, int nbuck) {
    cg::grid_group grid = cg::this_grid();
    __shared__ int l0[512];
    __shared__ int l1[512];
    __shared__ int l2[256];
    int t = threadIdx.x;
    int blk = blockIdx.x;

    // ---- P1: per-chunk bucket histograms (dst & src) ----
    if (blk < nchunk) {
        for (int i = t; i < 512; i += 256) { l0[i] = 0; l1[i] = 0; }
        __syncthreads();
        int base = blk * ECHUNK;
        for (int i = t * 4; i < ECHUNK; i += 1024) {   // int4 loads; E%4==0
            int e = base + i;
            if (e < E) {
                int4 d4 = *(const int4*)(ed + e);
                int4 s4 = *(const int4*)(es + e);
                atomicAdd(&l0[d4.x >> 8], 1); atomicAdd(&l0[d4.y >> 8], 1);
                atomicAdd(&l0[d4.z >> 8], 1); atomicAdd(&l0[d4.w >> 8], 1);
                atomicAdd(&l1[s4.x >> 8], 1); atomicAdd(&l1[s4.y >> 8], 1);
                atomicAdd(&l1[s4.z >> 8], 1); atomicAdd(&l1[s4.w >> 8], 1);
            }
        }
        __syncthreads();
        int row = blk * nbuck;
        for (int i = t; i < nbuck; i += 256) {
            cntA_d[row + i] = l0[i];
            cntA_s[row + i] = l1[i];
        }
    }
    grid.sync();

    // ---- P2: per-bucket exclusive scan over chunks (dst & src) ----
    if (blk < nbuck) {
        scan_col(cntA_d, cntB_d, tot_d, blk, nchunk, nbuck, l2, t);
        scan_col(cntA_s, cntB_s, tot_s, blk, nchunk, nbuck, l2, t);
    }
    grid.sync();

    // ---- P3: bucket-base scans (block 0 only) ----
    if (blk == 0) {
        scan_base(tot_d, base_d, nbuck, l2, t);
        scan_base(tot_s, base_s, nbuck, l2, t);
    }
    grid.sync();

    // ---- P4: binpack (per chunk) ----
    if (blk < nchunk) {
        for (int i = t; i < nbuck; i += 256) {
            l0[i] = base_d[i] + cntB_d[i * nchunk + blk];
            l1[i] = base_s[i] + cntB_s[i * nchunk + blk];
        }
        __syncthreads();
        int base = blk * ECHUNK;
        for (int i = t * 4; i < ECHUNK; i += 1024) {
            int e = base + i;
            if (e < E) {
                int4 s4 = *(const int4*)(es + e);
                int4 d4 = *(const int4*)(ed + e);
                int pd, ps;
                pd = atomicAdd(&l0[d4.x >> 8], 1); bp_dst[pd] = s4.x | ((d4.x & 255) << 24);
                pd = atomicAdd(&l0[d4.y >> 8], 1); bp_dst[pd] = s4.y | ((d4.y & 255) << 24);
                pd = atomicAdd(&l0[d4.z >> 8], 1); bp_dst[pd] = s4.z | ((d4.z & 255) << 24);
                pd = atomicAdd(&l0[d4.w >> 8], 1); bp_dst[pd] = s4.w | ((d4.w & 255) << 24);
                ps = atomicAdd(&l1[s4.x >> 8], 1); bp_src[ps] = (unsigned char)(s4.x & 255);
                ps = atomicAdd(&l1[s4.y >> 8], 1); bp_src[ps] = (unsigned char)(s4.y & 255);
                ps = atomicAdd(&l1[s4.z >> 8], 1); bp_src[ps] = (unsigned char)(s4.z & 255);
                ps = atomicAdd(&l1[s4.w >> 8], 1); bp_src[ps] = (unsigned char)(s4.w & 255);
            }
        }
    }
    grid.sync();

    // ---- P5: fill (per bucket): out-degree + off + csr scatter ----
    if (blk < nbuck) {
        int node = (blk << 8) + t;

        // src side: out-degree counts
        l0[t] = 0;
        __syncthreads();
        int lo = base_s[blk], hi = base_s[blk + 1];
        for (int i = lo + t; i < hi; i += 256) atomicAdd(&l0[bp_src[i]], 1);
        __syncthreads();
        if (node < n) ds[node] = l0[t];
        __syncthreads();

        // dst side: counts -> scan -> off + csr fill
        l0[t] = 0;
        __syncthreads();
        lo = base_d[blk]; hi = base_d[blk + 1];
        for (int i = lo + t; i < hi; i += 256)
            atomicAdd(&l0[(int)((unsigned)bp_dst[i] >> 24)], 1);
        __syncthreads();
        int v = l0[t];
        l1[t] = v;
        __syncthreads();
        for (int d = 1; d < 256; d <<= 1) {
            int u = (t >= d) ? l1[t - d] : 0;
            __syncthreads();
            l1[t] += u;
            __syncthreads();
        }
        int obase = lo + l1[t] - v;
        if (node < n) off[node] = obase;
        l2[t] = obase;
        if (blk == 0 && t == 0) off[n] = E;
        __syncthreads();
        for (int i = lo + t; i < hi; i += 256) {
            int w = bp_dst[i];
            int src = w & 0xFFFFFF;
            int d = (int)((unsigned)w >> 24);
            int slot = atomicAdd(&l2[d], 1);
            csr[slot] = src;
        }
    }
}

// ---------------- x = bf16( rsqrt(out_deg) * (H @ W) ) via MFMA ----------------
__global__ __launch_bounds__(256) void gemm_kernel(const float* __restrict__ h,
                                                   const float* __restrict__ W,
                                                   const int* __restrict__ ds,
                                                   unsigned short* __restrict__ x, int n) {
    __shared__ unsigned short Wt[OUT_DIM][136];   // [col][k], 17.4 KB
    int tid = threadIdx.x;

    {   // stage W^T as bf16: W is [128][64] row-major
        const float4* W4 = (const float4*)W;
        for (int i = tid; i < IN_DIM * OUT_DIM / 4; i += 256) {
            float4 v = W4[i];
            int k = i >> 4, c = (i & 15) * 4;
            Wt[c + 0][k] = f2b(v.x);
            Wt[c + 1][k] = f2b(v.y);
            Wt[c + 2][k] = f2b(v.z);
            Wt[c + 3][k] = f2b(v.w);
        }
    }
    __syncthreads();

    int wid = tid >> 6, lane = tid & 63;
    int rbase = blockIdx.x * 64 + wid * 16;
    int row = rbase + (lane & 15);
    int kg = lane >> 4;                       // 0..3
    int rowc = min(row, n - 1);

    const float* hrow = h + (size_t)rowc * IN_DIM + kg * 8;
    float4 af[8];
#pragma unroll
    for (int ks = 0; ks < 4; ks++) {
        af[2 * ks]     = *(const float4*)(hrow + ks * 32);
        af[2 * ks + 1] = *(const float4*)(hrow + ks * 32 + 4);
    }
    short8 afr[4];
#pragma unroll
    for (int ks = 0; ks < 4; ks++) {
        afr[ks][0] = (short)f2b(af[2 * ks].x);
        afr[ks][1] = (short)f2b(af[2 * ks].y);
        afr[ks][2] = (short)f2b(af[2 * ks].z);
        afr[ks][3] = (short)f2b(af[2 * ks].w);
        afr[ks][4] = (short)f2b(af[2 * ks + 1].x);
        afr[ks][5] = (short)f2b(af[2 * ks + 1].y);
        afr[ks][6] = (short)f2b(af[2 * ks + 1].z);
        afr[ks][7] = (short)f2b(af[2 * ks + 1].w);
    }

    floatx4 acc[4];
#pragma unroll
    for (int gf = 0; gf < 4; gf++) acc[gf] = (floatx4){0.f, 0.f, 0.f, 0.f};

#pragma unroll
    for (int ks = 0; ks < 4; ks++) {
#pragma unroll
        for (int gf = 0; gf < 4; gf++) {
            int col = gf * 16 + (lane & 15);
            short8 bfr = *(const short8*)&Wt[col][ks * 32 + kg * 8];
            acc[gf] = __builtin_amdgcn_mfma_f32_16x16x32_bf16(afr[ks], bfr, acc[gf], 0, 0, 0);
        }
    }

    // C/D layout: col = lane&15 (within gf*16), row = (lane>>4)*4 + reg
#pragma unroll
    for (int r = 0; r < 4; r++) {
        int orow = rbase + (lane >> 4) * 4 + r;
        if (orow < n) {
            float sc = rsqrtf((float)max(ds[orow], 1));
            unsigned short* xr = x + (size_t)orow * OUT_DIM + (lane & 15);
#pragma unroll
            for (int gf = 0; gf < 4; gf++)
                xr[gf * 16] = f2b(acc[gf][r] * sc);
        }
    }
}

// ---------------- gather-sum per dst node (bf16 x) + fused epilogue ----------------
// 8 lanes x 16B (8 bf16) per node; unroll-4 for memory-level parallelism.
__global__ __launch_bounds__(256) void gather_kernel(const unsigned short* __restrict__ x,
                                                     const int* __restrict__ csr,
                                                     const int* __restrict__ off,
                                                     const float* __restrict__ b,
                                                     float* __restrict__ out, int n) {
    int g = threadIdx.x >> 3;       // node slot in block (0..31)
    int p = threadIdx.x & 7;        // 8-bf16 column group
    int v = blockIdx.x * 32 + g;
    if (v >= n) return;
    int s0 = off[v], s1 = off[v + 1];
    float a0 = 0.f, a1 = 0.f, a2 = 0.f, a3 = 0.f, a4 = 0.f, a5 = 0.f, a6 = 0.f, a7 = 0.f;
    int j = s0;
    for (; j + 4 <= s1; j += 4) {
        int n0 = csr[j], n1 = csr[j + 1], n2 = csr[j + 2], n3 = csr[j + 3];
        uint4 w0 = ((const uint4*)(x + (size_t)n0 * OUT_DIM))[p];
        uint4 w1 = ((const uint4*)(x + (size_t)n1 * OUT_DIM))[p];
        uint4 w2 = ((const uint4*)(x + (size_t)n2 * OUT_DIM))[p];
        uint4 w3 = ((const uint4*)(x + (size_t)n3 * OUT_DIM))[p];
        a0 += (bf_lo(w0.x) + bf_lo(w1.x)) + (bf_lo(w2.x) + bf_lo(w3.x));
        a1 += (bf_hi(w0.x) + bf_hi(w1.x)) + (bf_hi(w2.x) + bf_hi(w3.x));
        a2 += (bf_lo(w0.y) + bf_lo(w1.y)) + (bf_lo(w2.y) + bf_lo(w3.y));
        a3 += (bf_hi(w0.y) + bf_hi(w1.y)) + (bf_hi(w2.y) + bf_hi(w3.y));
        a4 += (bf_lo(w0.z) + bf_lo(w1.z)) + (bf_lo(w2.z) + bf_lo(w3.z));
        a5 += (bf_hi(w0.z) + bf_hi(w1.z)) + (bf_hi(w2.z) + bf_hi(w3.z));
        a6 += (bf_lo(w0.w) + bf_lo(w1.w)) + (bf_lo(w2.w) + bf_lo(w3.w));
        a7 += (bf_hi(w0.w) + bf_hi(w1.w)) + (bf_hi(w2.w) + bf_hi(w3.w));
    }
    for (; j < s1; j++) {
        uint4 w0 = ((const uint4*)(x + (size_t)csr[j] * OUT_DIM))[p];
        a0 += bf_lo(w0.x); a1 += bf_hi(w0.x);
        a2 += bf_lo(w0.y); a3 += bf_hi(w0.y);
        a4 += bf_lo(w0.z); a5 += bf_hi(w0.z);
        a6 += bf_lo(w0.w); a7 += bf_hi(w0.w);
    }
    float nd = rsqrtf((float)max(s1 - s0, 1));
    float4 b0 = ((const float4*)b)[p * 2];
    float4 b1 = ((const float4*)b)[p * 2 + 1];
    float4 r0, r1;
    r0.x = a0 * nd + b0.x; r0.y = a1 * nd + b0.y;
    r0.z = a2 * nd + b0.z; r0.w = a3 * nd + b0.w;
    r1.x = a4 * nd + b1.x; r1.y = a5 * nd + b1.y;
    r1.z = a6 * nd + b1.z; r1.w = a7 * nd + b1.w;
    r0.x = (r0.x >= 0.f) ? r0.x : NEG_SLOPE * r0.x;
    r0.y = (r0.y >= 0.f) ? r0.y : NEG_SLOPE * r0.y;
    r0.z = (r0.z >= 0.f) ? r0.z : NEG_SLOPE * r0.z;
    r0.w = (r0.w >= 0.f) ? r0.w : NEG_SLOPE * r0.w;
    r1.x = (r1.x >= 0.f) ? r1.x : NEG_SLOPE * r1.x;
    r1.y = (r1.y >= 0.f) ? r1.y : NEG_SLOPE * r1.y;
    r1.z = (r1.z >= 0.f) ? r1.z : NEG_SLOPE * r1.z;
    r1.w = (r1.w >= 0.f) ? r1.w : NEG_SLOPE * r1.w;
    float* orow = out + (size_t)v * OUT_DIM + p * 8;
    *(float4*)orow = r0;
    *(float4*)(orow + 4) = r1;
}

extern "C" void kernel_launch(void* const* d_in, const int* in_sizes, int n_in,
                              void* d_out, int out_size, void* d_ws, size_t ws_size,
                              hipStream_t stream) {
    const float* h = (const float*)d_in[0];
    const float* W = (const float*)d_in[1];
    const float* b = (const float*)d_in[2];
    const int* esrc = (const int*)d_in[3];
    const int* edst = (const int*)d_in[4];
    int n = in_sizes[0] / IN_DIM;   // 100000
    int E = in_sizes[3];            // 1600000
    float* out = (float*)d_out;

    // ws layout: ds[n] | off[n+4] | csr[E] | x[n*64 bf16]
    char* ws = (char*)d_ws;
    int* ds  = (int*)ws;
    int* off = (int*)(ws + (size_t)n * 4);
    int* csr = (int*)(ws + (size_t)n * 8 + 16);
    char* xb = ws + (size_t)n * 8 + 16 + (size_t)E * 4;
    unsigned short* x = (unsigned short*)xb;

    int nchunk = (E + ECHUNK - 1) / ECHUNK;   // 391
    int nbuck  = (n + 255) >> 8;              // 391

    // transients aliased into x region (12.8 MB; all consumed before gemm writes x):
    int* bp_dst = (int*)xb;                                   // 6.4 MB
    unsigned char* bp_src = (unsigned char*)(xb + 6600000);   // 1.6 MB
    int* cntA_d = (int*)(xb + 8400000);                       // 611 KB
    int* cntA_s = (int*)(xb + 9100000);
    int* cntB_d = (int*)(xb + 9800000);
    int* cntB_s = (int*)(xb + 10500000);
    int* tot_d  = (int*)(xb + 11200000);                      // nbuck+1
    int* tot_s  = (int*)(xb + 11210000);
    int* base_d = (int*)(xb + 11220000);                      // nbuck+1
    int* base_s = (int*)(xb + 11230000);

    int gsz = (nchunk > nbuck) ? nchunk : nbuck;   // 391
    void* args[] = {(void*)&esrc, (void*)&edst,
                    (void*)&cntA_d, (void*)&cntA_s, (void*)&cntB_d, (void*)&cntB_s,
                    (void*)&tot_d, (void*)&tot_s, (void*)&base_d, (void*)&base_s,
                    (void*)&bp_dst, (void*)&bp_src,
                    (void*)&ds, (void*)&off, (void*)&csr,
                    (void*)&n, (void*)&E, (void*)&nchunk, (void*)&nbuck};
    hipLaunchCooperativeKernel((const void*)build_kernel, dim3(gsz), dim3(256),
                               args, 0, stream);
    gemm_kernel<<<(n + 63) / 64, 256, 0, stream>>>(h, W, ds, x, n);
    gather_kernel<<<(n + 31) / 32, 256, 0, stream>>>(x, csr, off, b, out, n);
}

// Round 12
// 130.240 us; speedup vs baseline: 2.5994x; 2.5994x over previous
//
#include <hip/hip_runtime.h>

#define IN_DIM 128
#define OUT_DIM 64
#define NEG_SLOPE 0.01f
#define ECHUNK 4096       // edges per binning block
// bucket = node >> 8 (256 nodes per bucket); gather group = src >> 14 (8 groups)

typedef __attribute__((ext_vector_type(8))) short short8;
typedef __attribute__((ext_vector_type(4))) float floatx4;

// bf16 helpers: memory layout = 16-bit, value = bits<<16
__device__ inline float bf_lo(unsigned u) { union { unsigned i; float f; } c; c.i = u << 16; return c.f; }
__device__ inline float bf_hi(unsigned u) { union { unsigned i; float f; } c; c.i = u & 0xFFFF0000u; return c.f; }
__device__ inline unsigned short f2b(float f) {
    union { float f; unsigned i; } c; c.f = f;
    unsigned u = c.i + 0x7FFFu + ((c.i >> 16) & 1u);   // round-to-nearest-even
    return (unsigned short)(u >> 16);
}

// ---------------- per-chunk bucket histograms (dst and src), LDS only ----------------
__global__ __launch_bounds__(256) void hist_kernel(
    const int* __restrict__ es, const int* __restrict__ ed,
    int* __restrict__ cntA_d, int* __restrict__ cntA_s, int E, int nbuck) {
    __shared__ int hd[512];
    __shared__ int hs[512];
    int t = threadIdx.x;
    for (int i = t; i < nbuck; i += 256) { hd[i] = 0; hs[i] = 0; }
    __syncthreads();
    int base = blockIdx.x * ECHUNK;
    for (int i = t * 4; i < ECHUNK; i += 1024) {   // int4 loads; E%4==0
        int e = base + i;
        if (e < E) {
            int4 d4 = *(const int4*)(ed + e);
            int4 s4 = *(const int4*)(es + e);
            atomicAdd(&hd[d4.x >> 8], 1); atomicAdd(&hd[d4.y >> 8], 1);
            atomicAdd(&hd[d4.z >> 8], 1); atomicAdd(&hd[d4.w >> 8], 1);
            atomicAdd(&hs[s4.x >> 8], 1); atomicAdd(&hs[s4.y >> 8], 1);
            atomicAdd(&hs[s4.z >> 8], 1); atomicAdd(&hs[s4.w >> 8], 1);
        }
    }
    __syncthreads();
    int row = blockIdx.x * nbuck;
    for (int i = t; i < nbuck; i += 256) {
        cntA_d[row + i] = hd[i];
        cntA_s[row + i] = hs[i];
    }
}

// ---------------- per-bucket exclusive scan over chunks + bucket totals ----------------
__global__ __launch_bounds__(512) void cntscan_kernel(
    const int* __restrict__ cntA_d, const int* __restrict__ cntA_s,
    int* __restrict__ cntB_d, int* __restrict__ cntB_s,
    int* __restrict__ tot_d, int* __restrict__ tot_s,
    int nchunk, int nbuck) {
    __shared__ int s[512];
    int t = threadIdx.x;
    int bid = blockIdx.x;
    const int* cntA = (bid < nbuck) ? cntA_d : cntA_s;
    int* cntB = (bid < nbuck) ? cntB_d : cntB_s;
    int* tot = (bid < nbuck) ? tot_d : tot_s;
    int b = (bid < nbuck) ? bid : bid - nbuck;
    int v = (t < nchunk) ? cntA[t * nbuck + b] : 0;
    s[t] = v;
    __syncthreads();
    for (int d = 1; d < 512; d <<= 1) {
        int u = (t >= d) ? s[t - d] : 0;
        __syncthreads();
        s[t] += u;
        __syncthreads();
    }
    if (t < nchunk) cntB[b * nchunk + t] = s[t] - v;
    if (t == 511) tot[b] = s[511];
}

// ---------------- exclusive scan over buckets -> bucket bases ----------------
__global__ __launch_bounds__(512) void base_kernel(
    const int* __restrict__ tot_d, const int* __restrict__ tot_s,
    int* __restrict__ base_d, int* __restrict__ base_s, int nbuck) {
    __shared__ int s[512];
    int t = threadIdx.x;
    for (int which = 0; which < 2; ++which) {
        const int* tot = which ? tot_s : tot_d;
        int* base = which ? base_s : base_d;
        int v = (t < nbuck) ? tot[t] : 0;
        s[t] = v;
        __syncthreads();
        for (int d = 1; d < 512; d <<= 1) {
            int u = (t >= d) ? s[t - d] : 0;
            __syncthreads();
            s[t] += u;
            __syncthreads();
        }
        if (t < nbuck) base[t] = s[t] - v;
        if (t == nbuck - 1) base[nbuck] = s[t];
        __syncthreads();
    }
}

// ---------------- bin edges by dst-bucket (packed) and src-bucket (byte) ----------------
__global__ __launch_bounds__(256) void binpack_kernel(
    const int* __restrict__ es, const int* __restrict__ ed,
    const int* __restrict__ base_d, const int* __restrict__ base_s,
    const int* __restrict__ cntB_d, const int* __restrict__ cntB_s,
    int* __restrict__ bp_dst, unsigned char* __restrict__ bp_src,
    int E, int nchunk, int nbuck) {
    __shared__ int ld[512];
    __shared__ int ls[512];
    int t = threadIdx.x;
    int c = blockIdx.x;
    for (int i = t; i < nbuck; i += 256) {
        ld[i] = base_d[i] + cntB_d[i * nchunk + c];
        ls[i] = base_s[i] + cntB_s[i * nchunk + c];
    }
    __syncthreads();
    int base = c * ECHUNK;
    for (int i = t * 4; i < ECHUNK; i += 1024) {   // int4 loads; E%4==0
        int e = base + i;
        if (e < E) {
            int4 s4 = *(const int4*)(es + e);
            int4 d4 = *(const int4*)(ed + e);
            int pd, ps;
            pd = atomicAdd(&ld[d4.x >> 8], 1); bp_dst[pd] = s4.x | ((d4.x & 255) << 24);
            pd = atomicAdd(&ld[d4.y >> 8], 1); bp_dst[pd] = s4.y | ((d4.y & 255) << 24);
            pd = atomicAdd(&ld[d4.z >> 8], 1); bp_dst[pd] = s4.z | ((d4.z & 255) << 24);
            pd = atomicAdd(&ld[d4.w >> 8], 1); bp_dst[pd] = s4.w | ((d4.w & 255) << 24);
            ps = atomicAdd(&ls[s4.x >> 8], 1); bp_src[ps] = (unsigned char)(s4.x & 255);
            ps = atomicAdd(&ls[s4.y >> 8], 1); bp_src[ps] = (unsigned char)(s4.y & 255);
            ps = atomicAdd(&ls[s4.z >> 8], 1); bp_src[ps] = (unsigned char)(s4.z & 255);
            ps = atomicAdd(&ls[s4.w >> 8], 1); bp_src[ps] = (unsigned char)(s4.w & 255);
        }
    }
}

// ---------------- merged fill: out-degree + off + GROUP-SORTED csr scatter ----------------
// csr within each node's segment is ordered by src-group (src>>14, 8 groups of
// 16384 nodes = 2.1 MB of x each). All gather waves then sweep x slice-by-slice
// in the same order -> concurrent random reads concentrate into an L2-resident
// slice ("soft phasing", no syncs needed).
__global__ __launch_bounds__(256) void fill_kernel(
    const int* __restrict__ bp_dst, const unsigned char* __restrict__ bp_src,
    const int* __restrict__ base_d, const int* __restrict__ base_s,
    int* __restrict__ ds, int* __restrict__ off, int* __restrict__ csr,
    int n, int E) {
    __shared__ int cnt[2048];   // [node_in_bucket][group] counts -> cursors
    __shared__ int s[256];
    __shared__ int l0[256];
    int t = threadIdx.x;
    int bkt = blockIdx.x;
    int node = (bkt << 8) + t;

    // --- src side: out-degree counts ---
    l0[t] = 0;
    __syncthreads();
    int lo = base_s[bkt], hi = base_s[bkt + 1];
    for (int i = lo + t; i < hi; i += 256) atomicAdd(&l0[bp_src[i]], 1);
    __syncthreads();
    if (node < n) ds[node] = l0[t];

    // --- dst side: per-(node,group) histogram ---
    for (int i = t; i < 2048; i += 256) cnt[i] = 0;
    __syncthreads();
    lo = base_d[bkt]; hi = base_d[bkt + 1];
    for (int i = lo + t; i < hi; i += 256) {
        int w = bp_dst[i];
        int src = w & 0xFFFFFF;
        int d = (int)((unsigned)w >> 24);
        atomicAdd(&cnt[d * 8 + (src >> 14)], 1);
    }
    __syncthreads();

    // --- 2048-wide exclusive scan: thread t owns node t's 8 group slots ---
    int loc[8];
    int tsum = 0;
#pragma unroll
    for (int g = 0; g < 8; g++) { loc[g] = cnt[t * 8 + g]; tsum += loc[g]; }
    s[t] = tsum;
    __syncthreads();
    for (int d = 1; d < 256; d <<= 1) {
        int u = (t >= d) ? s[t - d] : 0;
        __syncthreads();
        s[t] += u;
        __syncthreads();
    }
    int run = lo + s[t] - tsum;     // start of node t's segment within csr
    if (node < n) off[node] = run;
    if (bkt == 0 && t == 0) off[n] = E;
#pragma unroll
    for (int g = 0; g < 8; g++) { cnt[t * 8 + g] = run; run += loc[g]; }
    __syncthreads();

    // --- scatter with per-(node,group) cursors ---
    for (int i = lo + t; i < hi; i += 256) {
        int w = bp_dst[i];
        int src = w & 0xFFFFFF;
        int d = (int)((unsigned)w >> 24);
        int slot = atomicAdd(&cnt[d * 8 + (src >> 14)], 1);
        csr[slot] = src;
    }
}

// ---------------- x = bf16( rsqrt(out_deg) * (H @ W) ) via MFMA ----------------
__global__ __launch_bounds__(256) void gemm_kernel(const float* __restrict__ h,
                                                   const float* __restrict__ W,
                                                   const int* __restrict__ ds,
                                                   unsigned short* __restrict__ x, int n) {
    __shared__ unsigned short Wt[OUT_DIM][136];   // [col][k], 17.4 KB
    int tid = threadIdx.x;

    {   // stage W^T as bf16: W is [128][64] row-major
        const float4* W4 = (const float4*)W;
        for (int i = tid; i < IN_DIM * OUT_DIM / 4; i += 256) {
            float4 v = W4[i];
            int k = i >> 4, c = (i & 15) * 4;
            Wt[c + 0][k] = f2b(v.x);
            Wt[c + 1][k] = f2b(v.y);
            Wt[c + 2][k] = f2b(v.z);
            Wt[c + 3][k] = f2b(v.w);
        }
    }
    __syncthreads();

    int wid = tid >> 6, lane = tid & 63;
    int rbase = blockIdx.x * 64 + wid * 16;
    int row = rbase + (lane & 15);
    int kg = lane >> 4;                       // 0..3
    int rowc = min(row, n - 1);

    const float* hrow = h + (size_t)rowc * IN_DIM + kg * 8;
    float4 af[8];
#pragma unroll
    for (int ks = 0; ks < 4; ks++) {
        af[2 * ks]     = *(const float4*)(hrow + ks * 32);
        af[2 * ks + 1] = *(const float4*)(hrow + ks * 32 + 4);
    }
    short8 afr[4];
#pragma unroll
    for (int ks = 0; ks < 4; ks++) {
        afr[ks][0] = (short)f2b(af[2 * ks].x);
        afr[ks][1] = (short)f2b(af[2 * ks].y);
        afr[ks][2] = (short)f2b(af[2 * ks].z);
        afr[ks][3] = (short)f2b(af[2 * ks].w);
        afr[ks][4] = (short)f2b(af[2 * ks + 1].x);
        afr[ks][5] = (short)f2b(af[2 * ks + 1].y);
        afr[ks][6] = (short)f2b(af[2 * ks + 1].z);
        afr[ks][7] = (short)f2b(af[2 * ks + 1].w);
    }

    floatx4 acc[4];
#pragma unroll
    for (int gf = 0; gf < 4; gf++) acc[gf] = (floatx4){0.f, 0.f, 0.f, 0.f};

#pragma unroll
    for (int ks = 0; ks < 4; ks++) {
#pragma unroll
        for (int gf = 0; gf < 4; gf++) {
            int col = gf * 16 + (lane & 15);
            short8 bfr = *(const short8*)&Wt[col][ks * 32 + kg * 8];
            acc[gf] = __builtin_amdgcn_mfma_f32_16x16x32_bf16(afr[ks], bfr, acc[gf], 0, 0, 0);
        }
    }

    // C/D layout: col = lane&15 (within gf*16), row = (lane>>4)*4 + reg
#pragma unroll
    for (int r = 0; r < 4; r++) {
        int orow = rbase + (lane >> 4) * 4 + r;
        if (orow < n) {
            float sc = rsqrtf((float)max(ds[orow], 1));
            unsigned short* xr = x + (size_t)orow * OUT_DIM + (lane & 15);
#pragma unroll
            for (int gf = 0; gf < 4; gf++)
                xr[gf * 16] = f2b(acc[gf][r] * sc);
        }
    }
}

// ---------------- gather-sum per dst node (bf16 x) + fused epilogue ----------------
// 8 lanes x 16B (8 bf16) per node; unroll-4 for memory-level parallelism.
__global__ __launch_bounds__(256) void gather_kernel(const unsigned short* __restrict__ x,
                                                     const int* __restrict__ csr,
                                                     const int* __restrict__ off,
                                                     const float* __restrict__ b,
                                                     float* __restrict__ out, int n) {
    int g = threadIdx.x >> 3;       // node slot in block (0..31)
    int p = threadIdx.x & 7;        // 8-bf16 column group
    int v = blockIdx.x * 32 + g;
    if (v >= n) return;
    int s0 = off[v], s1 = off[v + 1];
    float a0 = 0.f, a1 = 0.f, a2 = 0.f, a3 = 0.f, a4 = 0.f, a5 = 0.f, a6 = 0.f, a7 = 0.f;
    int j = s0;
    for (; j + 4 <= s1; j += 4) {
        int n0 = csr[j], n1 = csr[j + 1], n2 = csr[j + 2], n3 = csr[j + 3];
        uint4 w0 = ((const uint4*)(x + (size_t)n0 * OUT_DIM))[p];
        uint4 w1 = ((const uint4*)(x + (size_t)n1 * OUT_DIM))[p];
        uint4 w2 = ((const uint4*)(x + (size_t)n2 * OUT_DIM))[p];
        uint4 w3 = ((const uint4*)(x + (size_t)n3 * OUT_DIM))[p];
        a0 += (bf_lo(w0.x) + bf_lo(w1.x)) + (bf_lo(w2.x) + bf_lo(w3.x));
        a1 += (bf_hi(w0.x) + bf_hi(w1.x)) + (bf_hi(w2.x) + bf_hi(w3.x));
        a2 += (bf_lo(w0.y) + bf_lo(w1.y)) + (bf_lo(w2.y) + bf_lo(w3.y));
        a3 += (bf_hi(w0.y) + bf_hi(w1.y)) + (bf_hi(w2.y) + bf_hi(w3.y));
        a4 += (bf_lo(w0.z) + bf_lo(w1.z)) + (bf_lo(w2.z) + bf_lo(w3.z));
        a5 += (bf_hi(w0.z) + bf_hi(w1.z)) + (bf_hi(w2.z) + bf_hi(w3.z));
        a6 += (bf_lo(w0.w) + bf_lo(w1.w)) + (bf_lo(w2.w) + bf_lo(w3.w));
        a7 += (bf_hi(w0.w) + bf_hi(w1.w)) + (bf_hi(w2.w) + bf_hi(w3.w));
    }
    for (; j < s1; j++) {
        uint4 w0 = ((const uint4*)(x + (size_t)csr[j] * OUT_DIM))[p];
        a0 += bf_lo(w0.x); a1 += bf_hi(w0.x);
        a2 += bf_lo(w0.y); a3 += bf_hi(w0.y);
        a4 += bf_lo(w0.z); a5 += bf_hi(w0.z);
        a6 += bf_lo(w0.w); a7 += bf_hi(w0.w);
    }
    float nd = rsqrtf((float)max(s1 - s0, 1));
    float4 b0 = ((const float4*)b)[p * 2];
    float4 b1 = ((const float4*)b)[p * 2 + 1];
    float4 r0, r1;
    r0.x = a0 * nd + b0.x; r0.y = a1 * nd + b0.y;
    r0.z = a2 * nd + b0.z; r0.w = a3 * nd + b0.w;
    r1.x = a4 * nd + b1.x; r1.y = a5 * nd + b1.y;
    r1.z = a6 * nd + b1.z; r1.w = a7 * nd + b1.w;
    r0.x = (r0.x >= 0.f) ? r0.x : NEG_SLOPE * r0.x;
    r0.y = (r0.y >= 0.f) ? r0.y : NEG_SLOPE * r0.y;
    r0.z = (r0.z >= 0.f) ? r0.z : NEG_SLOPE * r0.z;
    r0.w = (r0.w >= 0.f) ? r0.w : NEG_SLOPE * r0.w;
    r1.x = (r1.x >= 0.f) ? r1.x : NEG_SLOPE * r1.x;
    r1.y = (r1.y >= 0.f) ? r1.y : NEG_SLOPE * r1.y;
    r1.z = (r1.z >= 0.f) ? r1.z : NEG_SLOPE * r1.z;
    r1.w = (r1.w >= 0.f) ? r1.w : NEG_SLOPE * r1.w;
    float* orow = out + (size_t)v * OUT_DIM + p * 8;
    *(float4*)orow = r0;
    *(float4*)(orow + 4) = r1;
}

extern "C" void kernel_launch(void* const* d_in, const int* in_sizes, int n_in,
                              void* d_out, int out_size, void* d_ws, size_t ws_size,
                              hipStream_t stream) {
    const float* h = (const float*)d_in[0];
    const float* W = (const float*)d_in[1];
    const float* b = (const float*)d_in[2];
    const int* esrc = (const int*)d_in[3];
    const int* edst = (const int*)d_in[4];
    int n = in_sizes[0] / IN_DIM;   // 100000
    int E = in_sizes[3];            // 1600000
    float* out = (float*)d_out;

    // ws layout: ds[n] | off[n+4] | csr[E] | x[n*64 bf16]
    char* ws = (char*)d_ws;
    int* ds  = (int*)ws;
    int* off = (int*)(ws + (size_t)n * 4);
    int* csr = (int*)(ws + (size_t)n * 8 + 16);
    char* xb = ws + (size_t)n * 8 + 16 + (size_t)E * 4;
    unsigned short* x = (unsigned short*)xb;

    int nchunk = (E + ECHUNK - 1) / ECHUNK;   // 391
    int nbuck  = (n + 255) >> 8;              // 391

    // transients aliased into x region (12.8 MB; all consumed before gemm writes x):
    int* bp_dst = (int*)xb;                                   // 6.4 MB
    unsigned char* bp_src = (unsigned char*)(xb + 6600000);   // 1.6 MB
    int* cntA_d = (int*)(xb + 8400000);                       // 611 KB
    int* cntA_s = (int*)(xb + 9100000);
    int* cntB_d = (int*)(xb + 9800000);
    int* cntB_s = (int*)(xb + 10500000);
    int* tot_d  = (int*)(xb + 11200000);                      // nbuck+1
    int* tot_s  = (int*)(xb + 11210000);
    int* base_d = (int*)(xb + 11220000);                      // nbuck+1
    int* base_s = (int*)(xb + 11230000);

    hist_kernel<<<nchunk, 256, 0, stream>>>(esrc, edst, cntA_d, cntA_s, E, nbuck);
    cntscan_kernel<<<2 * nbuck, 512, 0, stream>>>(cntA_d, cntA_s, cntB_d, cntB_s,
                                                  tot_d, tot_s, nchunk, nbuck);
    base_kernel<<<1, 512, 0, stream>>>(tot_d, tot_s, base_d, base_s, nbuck);
    binpack_kernel<<<nchunk, 256, 0, stream>>>(esrc, edst, base_d, base_s,
                                               cntB_d, cntB_s, bp_dst, bp_src,
                                               E, nchunk, nbuck);
    fill_kernel<<<nbuck, 256, 0, stream>>>(bp_dst, bp_src, base_d, base_s,
                                           ds, off, csr, n, E);
    gemm_kernel<<<(n + 63) / 64, 256, 0, stream>>>(h, W, ds, x, n);
    gather_kernel<<<(n + 31) / 32, 256, 0, stream>>>(x, csr, off, b, out, n);
}

// Round 13
// 129.729 us; speedup vs baseline: 2.6096x; 1.0039x over previous
//
#include <hip/hip_runtime.h>

#define IN_DIM 128
#define OUT_DIM 64
#define NEG_SLOPE 0.01f
#define ECHUNK 4096       // edges per binning block
// bucket = node >> 8 (256 nodes per bucket); gather group = src >> 14 (8 groups)

typedef __attribute__((ext_vector_type(8))) short short8;
typedef __attribute__((ext_vector_type(4))) float floatx4;

// bf16 helpers: memory layout = 16-bit, value = bits<<16
__device__ inline float bf_lo(unsigned u) { union { unsigned i; float f; } c; c.i = u << 16; return c.f; }
__device__ inline float bf_hi(unsigned u) { union { unsigned i; float f; } c; c.i = u & 0xFFFF0000u; return c.f; }
__device__ inline unsigned short f2b(float f) {
    union { float f; unsigned i; } c; c.f = f;
    unsigned u = c.i + 0x7FFFu + ((c.i >> 16) & 1u);   // round-to-nearest-even
    return (unsigned short)(u >> 16);
}

// ---------------- per-chunk bucket histograms (dst and src), LDS only ----------------
__global__ __launch_bounds__(256) void hist_kernel(
    const int* __restrict__ es, const int* __restrict__ ed,
    int* __restrict__ cntA_d, int* __restrict__ cntA_s, int E, int nbuck) {
    __shared__ int hd[512];
    __shared__ int hs[512];
    int t = threadIdx.x;
    for (int i = t; i < nbuck; i += 256) { hd[i] = 0; hs[i] = 0; }
    __syncthreads();
    int base = blockIdx.x * ECHUNK;
    for (int i = t * 4; i < ECHUNK; i += 1024) {   // int4 loads; E%4==0
        int e = base + i;
        if (e < E) {
            int4 d4 = *(const int4*)(ed + e);
            int4 s4 = *(const int4*)(es + e);
            atomicAdd(&hd[d4.x >> 8], 1); atomicAdd(&hd[d4.y >> 8], 1);
            atomicAdd(&hd[d4.z >> 8], 1); atomicAdd(&hd[d4.w >> 8], 1);
            atomicAdd(&hs[s4.x >> 8], 1); atomicAdd(&hs[s4.y >> 8], 1);
            atomicAdd(&hs[s4.z >> 8], 1); atomicAdd(&hs[s4.w >> 8], 1);
        }
    }
    __syncthreads();
    int row = blockIdx.x * nbuck;
    for (int i = t; i < nbuck; i += 256) {
        cntA_d[row + i] = hd[i];
        cntA_s[row + i] = hs[i];
    }
}

// ---------------- per-bucket exclusive scan over chunks (dst AND src) + totals ----------------
__global__ __launch_bounds__(512) void cntscan_kernel(
    const int* __restrict__ cntA_d, const int* __restrict__ cntA_s,
    int* __restrict__ cntB_d, int* __restrict__ cntB_s,
    int* __restrict__ tot_d, int* __restrict__ tot_s,
    int nchunk, int nbuck) {
    __shared__ int s[512];
    int t = threadIdx.x;
    int b = blockIdx.x;
    // dst column
    int v = (t < nchunk) ? cntA_d[t * nbuck + b] : 0;
    s[t] = v;
    __syncthreads();
    for (int d = 1; d < 512; d <<= 1) {
        int u = (t >= d) ? s[t - d] : 0;
        __syncthreads();
        s[t] += u;
        __syncthreads();
    }
    if (t < nchunk) cntB_d[b * nchunk + t] = s[t] - v;
    if (t == 511) tot_d[b] = s[511];
    __syncthreads();
    // src column
    v = (t < nchunk) ? cntA_s[t * nbuck + b] : 0;
    s[t] = v;
    __syncthreads();
    for (int d = 1; d < 512; d <<= 1) {
        int u = (t >= d) ? s[t - d] : 0;
        __syncthreads();
        s[t] += u;
        __syncthreads();
    }
    if (t < nchunk) cntB_s[b * nchunk + t] = s[t] - v;
    if (t == 511) tot_s[b] = s[511];
}

// in-block exclusive scan of tot[0..m) into bd[0..m] (bd[m]=total), 2 elems/thread
__device__ inline void block_base_scan(const int* __restrict__ tot, int* bd, int m,
                                       int* ps, int t) {
    int j0 = 2 * t, j1 = 2 * t + 1;
    int a0 = (j0 < m) ? tot[j0] : 0;
    int a1 = (j1 < m) ? tot[j1] : 0;
    ps[t] = a0 + a1;
    __syncthreads();
    for (int d = 1; d < 256; d <<= 1) {
        int u = (t >= d) ? ps[t - d] : 0;
        __syncthreads();
        ps[t] += u;
        __syncthreads();
    }
    int excl = ps[t] - (a0 + a1);
    if (j0 < m) bd[j0] = excl;
    if (j1 < m) bd[j1] = excl + a0;
    if (t == 255) bd[m] = ps[255];
    __syncthreads();
}

// ---------------- bin edges by dst-bucket (packed) and src-bucket (byte) ----------------
// Bucket bases computed in-block from tot arrays (base_kernel folded in);
// block 0 publishes them to global for fill_kernel.
__global__ __launch_bounds__(256) void binpack_kernel(
    const int* __restrict__ es, const int* __restrict__ ed,
    const int* __restrict__ tot_d, const int* __restrict__ tot_s,
    const int* __restrict__ cntB_d, const int* __restrict__ cntB_s,
    int* __restrict__ bp_dst, unsigned char* __restrict__ bp_src,
    int* __restrict__ base_d, int* __restrict__ base_s,
    int E, int nchunk, int nbuck) {
    __shared__ int bd[512];
    __shared__ int bs[512];
    __shared__ int ld[512];
    __shared__ int ls[512];
    __shared__ int ps[256];
    int t = threadIdx.x;
    int c = blockIdx.x;

    block_base_scan(tot_d, bd, nbuck, ps, t);
    block_base_scan(tot_s, bs, nbuck, ps, t);
    if (c == 0) {   // publish for fill_kernel
        for (int i = t; i <= nbuck; i += 256) { base_d[i] = bd[i]; base_s[i] = bs[i]; }
    }
    for (int i = t; i < nbuck; i += 256) {
        ld[i] = bd[i] + cntB_d[i * nchunk + c];
        ls[i] = bs[i] + cntB_s[i * nchunk + c];
    }
    __syncthreads();
    int base = c * ECHUNK;
    for (int i = t * 4; i < ECHUNK; i += 1024) {   // int4 loads; E%4==0
        int e = base + i;
        if (e < E) {
            int4 s4 = *(const int4*)(es + e);
            int4 d4 = *(const int4*)(ed + e);
            int pd, px;
            pd = atomicAdd(&ld[d4.x >> 8], 1); bp_dst[pd] = s4.x | ((d4.x & 255) << 24);
            pd = atomicAdd(&ld[d4.y >> 8], 1); bp_dst[pd] = s4.y | ((d4.y & 255) << 24);
            pd = atomicAdd(&ld[d4.z >> 8], 1); bp_dst[pd] = s4.z | ((d4.z & 255) << 24);
            pd = atomicAdd(&ld[d4.w >> 8], 1); bp_dst[pd] = s4.w | ((d4.w & 255) << 24);
            px = atomicAdd(&ls[s4.x >> 8], 1); bp_src[px] = (unsigned char)(s4.x & 255);
            px = atomicAdd(&ls[s4.y >> 8], 1); bp_src[px] = (unsigned char)(s4.y & 255);
            px = atomicAdd(&ls[s4.z >> 8], 1); bp_src[px] = (unsigned char)(s4.z & 255);
            px = atomicAdd(&ls[s4.w >> 8], 1); bp_src[px] = (unsigned char)(s4.w & 255);
        }
    }
}

// ---------------- merged fill: out-degree + off + GROUP-SORTED csr scatter ----------------
// csr within each node's segment ordered by src-group (src>>14, 8 groups of 16384
// nodes = 2.1 MB of x each) -> gather waves sweep x slice-by-slice (soft phasing).
__global__ __launch_bounds__(256) void fill_kernel(
    const int* __restrict__ bp_dst, const unsigned char* __restrict__ bp_src,
    const int* __restrict__ base_d, const int* __restrict__ base_s,
    int* __restrict__ ds, int* __restrict__ off, int* __restrict__ csr,
    int n, int E) {
    __shared__ int cnt[2048];   // [node_in_bucket][group] counts -> cursors
    __shared__ int s[256];
    __shared__ int l0[256];
    int t = threadIdx.x;
    int bkt = blockIdx.x;
    int node = (bkt << 8) + t;

    // --- src side: out-degree counts ---
    l0[t] = 0;
    __syncthreads();
    int lo = base_s[bkt], hi = base_s[bkt + 1];
    for (int i = lo + t; i < hi; i += 256) atomicAdd(&l0[bp_src[i]], 1);
    __syncthreads();
    if (node < n) ds[node] = l0[t];

    // --- dst side: per-(node,group) histogram ---
    for (int i = t; i < 2048; i += 256) cnt[i] = 0;
    __syncthreads();
    lo = base_d[bkt]; hi = base_d[bkt + 1];
    for (int i = lo + t; i < hi; i += 256) {
        int w = bp_dst[i];
        int src = w & 0xFFFFFF;
        int d = (int)((unsigned)w >> 24);
        atomicAdd(&cnt[d * 8 + (src >> 14)], 1);
    }
    __syncthreads();

    // --- 2048-wide exclusive scan: thread t owns node t's 8 group slots ---
    int loc[8];
    int tsum = 0;
#pragma unroll
    for (int g = 0; g < 8; g++) { loc[g] = cnt[t * 8 + g]; tsum += loc[g]; }
    s[t] = tsum;
    __syncthreads();
    for (int d = 1; d < 256; d <<= 1) {
        int u = (t >= d) ? s[t - d] : 0;
        __syncthreads();
        s[t] += u;
        __syncthreads();
    }
    int run = lo + s[t] - tsum;     // start of node t's segment within csr
    if (node < n) off[node] = run;
    if (bkt == 0 && t == 0) off[n] = E;
#pragma unroll
    for (int g = 0; g < 8; g++) { cnt[t * 8 + g] = run; run += loc[g]; }
    __syncthreads();

    // --- scatter with per-(node,group) cursors ---
    for (int i = lo + t; i < hi; i += 256) {
        int w = bp_dst[i];
        int src = w & 0xFFFFFF;
        int d = (int)((unsigned)w >> 24);
        int slot = atomicAdd(&cnt[d * 8 + (src >> 14)], 1);
        csr[slot] = src;
    }
}

// ---------------- x = bf16( rsqrt(out_deg) * (H @ W) ) via MFMA ----------------
__global__ __launch_bounds__(256) void gemm_kernel(const float* __restrict__ h,
                                                   const float* __restrict__ W,
                                                   const int* __restrict__ ds,
                                                   unsigned short* __restrict__ x, int n) {
    __shared__ unsigned short Wt[OUT_DIM][136];   // [col][k], 17.4 KB
    int tid = threadIdx.x;

    {   // stage W^T as bf16: W is [128][64] row-major
        const float4* W4 = (const float4*)W;
        for (int i = tid; i < IN_DIM * OUT_DIM / 4; i += 256) {
            float4 v = W4[i];
            int k = i >> 4, c = (i & 15) * 4;
            Wt[c + 0][k] = f2b(v.x);
            Wt[c + 1][k] = f2b(v.y);
            Wt[c + 2][k] = f2b(v.z);
            Wt[c + 3][k] = f2b(v.w);
        }
    }
    __syncthreads();

    int wid = tid >> 6, lane = tid & 63;
    int rbase = blockIdx.x * 64 + wid * 16;
    int row = rbase + (lane & 15);
    int kg = lane >> 4;                       // 0..3
    int rowc = min(row, n - 1);

    const float* hrow = h + (size_t)rowc * IN_DIM + kg * 8;
    float4 af[8];
#pragma unroll
    for (int ks = 0; ks < 4; ks++) {
        af[2 * ks]     = *(const float4*)(hrow + ks * 32);
        af[2 * ks + 1] = *(const float4*)(hrow + ks * 32 + 4);
    }
    short8 afr[4];
#pragma unroll
    for (int ks = 0; ks < 4; ks++) {
        afr[ks][0] = (short)f2b(af[2 * ks].x);
        afr[ks][1] = (short)f2b(af[2 * ks].y);
        afr[ks][2] = (short)f2b(af[2 * ks].z);
        afr[ks][3] = (short)f2b(af[2 * ks].w);
        afr[ks][4] = (short)f2b(af[2 * ks + 1].x);
        afr[ks][5] = (short)f2b(af[2 * ks + 1].y);
        afr[ks][6] = (short)f2b(af[2 * ks + 1].z);
        afr[ks][7] = (short)f2b(af[2 * ks + 1].w);
    }

    floatx4 acc[4];
#pragma unroll
    for (int gf = 0; gf < 4; gf++) acc[gf] = (floatx4){0.f, 0.f, 0.f, 0.f};

#pragma unroll
    for (int ks = 0; ks < 4; ks++) {
#pragma unroll
        for (int gf = 0; gf < 4; gf++) {
            int col = gf * 16 + (lane & 15);
            short8 bfr = *(const short8*)&Wt[col][ks * 32 + kg * 8];
            acc[gf] = __builtin_amdgcn_mfma_f32_16x16x32_bf16(afr[ks], bfr, acc[gf], 0, 0, 0);
        }
    }

    // C/D layout: col = lane&15 (within gf*16), row = (lane>>4)*4 + reg
#pragma unroll
    for (int r = 0; r < 4; r++) {
        int orow = rbase + (lane >> 4) * 4 + r;
        if (orow < n) {
            float sc = rsqrtf((float)max(ds[orow], 1));
            unsigned short* xr = x + (size_t)orow * OUT_DIM + (lane & 15);
#pragma unroll
            for (int gf = 0; gf < 4; gf++)
                xr[gf * 16] = f2b(acc[gf][r] * sc);
        }
    }
}

// ---------------- gather-sum per dst node (bf16 x) + fused epilogue ----------------
// 8 lanes x 16B (8 bf16) per node; unroll-4 for memory-level parallelism.
__global__ __launch_bounds__(256) void gather_kernel(const unsigned short* __restrict__ x,
                                                     const int* __restrict__ csr,
                                                     const int* __restrict__ off,
                                                     const float* __restrict__ b,
                                                     float* __restrict__ out, int n) {
    int g = threadIdx.x >> 3;       // node slot in block (0..31)
    int p = threadIdx.x & 7;        // 8-bf16 column group
    int v = blockIdx.x * 32 + g;
    if (v >= n) return;
    int s0 = off[v], s1 = off[v + 1];
    float a0 = 0.f, a1 = 0.f, a2 = 0.f, a3 = 0.f, a4 = 0.f, a5 = 0.f, a6 = 0.f, a7 = 0.f;
    int j = s0;
    for (; j + 4 <= s1; j += 4) {
        int n0 = csr[j], n1 = csr[j + 1], n2 = csr[j + 2], n3 = csr[j + 3];
        uint4 w0 = ((const uint4*)(x + (size_t)n0 * OUT_DIM))[p];
        uint4 w1 = ((const uint4*)(x + (size_t)n1 * OUT_DIM))[p];
        uint4 w2 = ((const uint4*)(x + (size_t)n2 * OUT_DIM))[p];
        uint4 w3 = ((const uint4*)(x + (size_t)n3 * OUT_DIM))[p];
        a0 += (bf_lo(w0.x) + bf_lo(w1.x)) + (bf_lo(w2.x) + bf_lo(w3.x));
        a1 += (bf_hi(w0.x) + bf_hi(w1.x)) + (bf_hi(w2.x) + bf_hi(w3.x));
        a2 += (bf_lo(w0.y) + bf_lo(w1.y)) + (bf_lo(w2.y) + bf_lo(w3.y));
        a3 += (bf_hi(w0.y) + bf_hi(w1.y)) + (bf_hi(w2.y) + bf_hi(w3.y));
        a4 += (bf_lo(w0.z) + bf_lo(w1.z)) + (bf_lo(w2.z) + bf_lo(w3.z));
        a5 += (bf_hi(w0.z) + bf_hi(w1.z)) + (bf_hi(w2.z) + bf_hi(w3.z));
        a6 += (bf_lo(w0.w) + bf_lo(w1.w)) + (bf_lo(w2.w) + bf_lo(w3.w));
        a7 += (bf_hi(w0.w) + bf_hi(w1.w)) + (bf_hi(w2.w) + bf_hi(w3.w));
    }
    for (; j < s1; j++) {
        uint4 w0 = ((const uint4*)(x + (size_t)csr[j] * OUT_DIM))[p];
        a0 += bf_lo(w0.x); a1 += bf_hi(w0.x);
        a2 += bf_lo(w0.y); a3 += bf_hi(w0.y);
        a4 += bf_lo(w0.z); a5 += bf_hi(w0.z);
        a6 += bf_lo(w0.w); a7 += bf_hi(w0.w);
    }
    float nd = rsqrtf((float)max(s1 - s0, 1));
    float4 b0 = ((const float4*)b)[p * 2];
    float4 b1 = ((const float4*)b)[p * 2 + 1];
    float4 r0, r1;
    r0.x = a0 * nd + b0.x; r0.y = a1 * nd + b0.y;
    r0.z = a2 * nd + b0.z; r0.w = a3 * nd + b0.w;
    r1.x = a4 * nd + b1.x; r1.y = a5 * nd + b1.y;
    r1.z = a6 * nd + b1.z; r1.w = a7 * nd + b1.w;
    r0.x = (r0.x >= 0.f) ? r0.x : NEG_SLOPE * r0.x;
    r0.y = (r0.y >= 0.f) ? r0.y : NEG_SLOPE * r0.y;
    r0.z = (r0.z >= 0.f) ? r0.z : NEG_SLOPE * r0.z;
    r0.w = (r0.w >= 0.f) ? r0.w : NEG_SLOPE * r0.w;
    r1.x = (r1.x >= 0.f) ? r1.x : NEG_SLOPE * r1.x;
    r1.y = (r1.y >= 0.f) ? r1.y : NEG_SLOPE * r1.y;
    r1.z = (r1.z >= 0.f) ? r1.z : NEG_SLOPE * r1.z;
    r1.w = (r1.w >= 0.f) ? r1.w : NEG_SLOPE * r1.w;
    float* orow = out + (size_t)v * OUT_DIM + p * 8;
    *(float4*)orow = r0;
    *(float4*)(orow + 4) = r1;
}

extern "C" void kernel_launch(void* const* d_in, const int* in_sizes, int n_in,
                              void* d_out, int out_size, void* d_ws, size_t ws_size,
                              hipStream_t stream) {
    const float* h = (const float*)d_in[0];
    const float* W = (const float*)d_in[1];
    const float* b = (const float*)d_in[2];
    const int* esrc = (const int*)d_in[3];
    const int* edst = (const int*)d_in[4];
    int n = in_sizes[0] / IN_DIM;   // 100000
    int E = in_sizes[3];            // 1600000
    float* out = (float*)d_out;

    // ws layout: ds[n] | off[n+4] | csr[E] | x[n*64 bf16]
    char* ws = (char*)d_ws;
    int* ds  = (int*)ws;
    int* off = (int*)(ws + (size_t)n * 4);
    int* csr = (int*)(ws + (size_t)n * 8 + 16);
    char* xb = ws + (size_t)n * 8 + 16 + (size_t)E * 4;
    unsigned short* x = (unsigned short*)xb;

    int nchunk = (E + ECHUNK - 1) / ECHUNK;   // 391
    int nbuck  = (n + 255) >> 8;              // 391

    // transients aliased into x region (12.8 MB; all consumed before gemm writes x):
    int* bp_dst = (int*)xb;                                   // 6.4 MB
    unsigned char* bp_src = (unsigned char*)(xb + 6600000);   // 1.6 MB
    int* cntA_d = (int*)(xb + 8400000);                       // 611 KB
    int* cntA_s = (int*)(xb + 9100000);
    int* cntB_d = (int*)(xb + 9800000);
    int* cntB_s = (int*)(xb + 10500000);
    int* tot_d  = (int*)(xb + 11200000);                      // nbuck+1
    int* tot_s  = (int*)(xb + 11210000);
    int* base_d = (int*)(xb + 11220000);                      // nbuck+1
    int* base_s = (int*)(xb + 11230000);

    hist_kernel<<<nchunk, 256, 0, stream>>>(esrc, edst, cntA_d, cntA_s, E, nbuck);
    cntscan_kernel<<<nbuck, 512, 0, stream>>>(cntA_d, cntA_s, cntB_d, cntB_s,
                                              tot_d, tot_s, nchunk, nbuck);
    binpack_kernel<<<nchunk, 256, 0, stream>>>(esrc, edst, tot_d, tot_s,
                                               cntB_d, cntB_s, bp_dst, bp_src,
                                               base_d, base_s, E, nchunk, nbuck);
    fill_kernel<<<nbuck, 256, 0, stream>>>(bp_dst, bp_src, base_d, base_s,
                                           ds, off, csr, n, E);
    gemm_kernel<<<(n + 63) / 64, 256, 0, stream>>>(h, W, ds, x, n);
    gather_kernel<<<(n + 31) / 32, 256, 0, stream>>>(x, csr, off, b, out, n);
}